// Round 1
// baseline (187.832 us; speedup 1.0000x reference)
//
#include <hip/hip_runtime.h>
#include <math.h>

// Problem constants (fixed shapes from reference setup_inputs)
#define BB    128      // batch
#define TT    64       // time
#define NSZ   57       // input matrix dim
#define NN    3249     // 57*57
#define MTOT  8192     // BB*TT
#define NOUT  17
#define RECT_EPS 1e-4f

// ws layout (floats)
#define WC_OFF   0                    // 114 floats: Wc = W1@W2@W3 (57x2)
#define C00_OFF  128                  // 3249 floats
#define C01_OFF  (128 + 3264)
#define C11_OFF  (128 + 2*3264)
#define A00_OFF  (128 + 3*3264)       // 8192 floats each
#define A01_OFF  (A00_OFF + MTOT)
#define A11_OFF  (A01_OFF + MTOT)

// ---------------------------------------------------------------------------
// Kernel 1: compute Wc = W1@W2@W3 (57x2) and coefficient arrays
//   c_ij[f] = Wc[p][i]*Wc[q][j],  f = p*57+q
// so that a_ij[m] = sum_f c_ij[f] * x[m,f]  ==  (Wc^T x_m Wc)[i][j].
// Single block; trivial cost.
// ---------------------------------------------------------------------------
__global__ __launch_bounds__(256) void prep_kernel(
    const float* __restrict__ W1, const float* __restrict__ W2,
    const float* __restrict__ W3, float* __restrict__ ws)
{
    __shared__ float W12[57 * 10];
    __shared__ float WcS[57 * 2];
    const int tid = threadIdx.x;

    for (int i = tid; i < 57 * 10; i += 256) {
        int p = i / 10, j = i % 10;
        float s = 0.f;
        #pragma unroll
        for (int k = 0; k < 20; ++k) s = fmaf(W1[p * 20 + k], W2[k * 10 + j], s);
        W12[i] = s;
    }
    __syncthreads();
    for (int i = tid; i < 57 * 2; i += 256) {
        int p = i / 2, j = i % 2;
        float s = 0.f;
        #pragma unroll
        for (int k = 0; k < 10; ++k) s = fmaf(W12[p * 10 + k], W3[k * 2 + j], s);
        WcS[i] = s;
        ws[WC_OFF + i] = s;
    }
    __syncthreads();
    float* c00 = ws + C00_OFF;
    float* c01 = ws + C01_OFF;
    float* c11 = ws + C11_OFF;
    for (int f = tid; f < NN; f += 256) {
        int p = f / 57, q = f % 57;
        float p0 = WcS[p * 2], p1 = WcS[p * 2 + 1];
        float q0 = WcS[q * 2], q1 = WcS[q * 2 + 1];
        c00[f] = p0 * q0;
        c01[f] = p0 * q1;   // a01 = sum Wc[p][0] x[p][q] Wc[q][1]
        c11[f] = p1 * q1;
    }
}

// ---------------------------------------------------------------------------
// Kernel 2 (dominant): a_ij[m] = dot(c_ij, x_m) over 3249 elements.
// Persistent blocks: coefficients live in 39 registers/thread, amortized
// over MTOT/grid matrices. Fully coalesced scalar loads of x (256B/wave).
// ---------------------------------------------------------------------------
#define PROJ_GRID 1024
__global__ __launch_bounds__(256) void proj_kernel(
    const float* __restrict__ x, float* __restrict__ ws)
{
    const float* __restrict__ c00 = ws + C00_OFF;
    const float* __restrict__ c01 = ws + C01_OFF;
    const float* __restrict__ c11 = ws + C11_OFF;
    float* __restrict__ a00 = ws + A00_OFF;
    float* __restrict__ a01 = ws + A01_OFF;
    float* __restrict__ a11 = ws + A11_OFF;

    const int tid = threadIdx.x;

    // Per-thread coefficient registers: f = tid + 256*i, i in [0,13)
    float k00[13], k01[13], k11[13];
    #pragma unroll
    for (int i = 0; i < 13; ++i) {
        int f = tid + 256 * i;
        if (f < NN) { k00[i] = c00[f]; k01[i] = c01[f]; k11[i] = c11[f]; }
        else        { k00[i] = 0.f;    k01[i] = 0.f;    k11[i] = 0.f;    }
    }

    __shared__ float red[4 * 3];

    for (int m = blockIdx.x; m < MTOT; m += PROJ_GRID) {
        const float* __restrict__ xm = x + (size_t)m * NN;
        float s00 = 0.f, s01 = 0.f, s11 = 0.f;
        // 12 full iterations: max f = 255 + 256*11 = 3071 < 3249
        #pragma unroll
        for (int i = 0; i < 12; ++i) {
            float xv = xm[tid + 256 * i];
            s00 = fmaf(k00[i], xv, s00);
            s01 = fmaf(k01[i], xv, s01);
            s11 = fmaf(k11[i], xv, s11);
        }
        // tail: f = tid + 3072 < 3249  <=>  tid < 177
        if (tid < NN - 3072) {
            float xv = xm[tid + 3072];
            s00 = fmaf(k00[12], xv, s00);
            s01 = fmaf(k01[12], xv, s01);
            s11 = fmaf(k11[12], xv, s11);
        }
        // wave (64-lane) shuffle reduction
        #pragma unroll
        for (int off = 32; off > 0; off >>= 1) {
            s00 += __shfl_down(s00, off);
            s01 += __shfl_down(s01, off);
            s11 += __shfl_down(s11, off);
        }
        const int lane = tid & 63, wv = tid >> 6;
        if (lane == 0) { red[wv * 3] = s00; red[wv * 3 + 1] = s01; red[wv * 3 + 2] = s11; }
        __syncthreads();
        if (tid == 0) {
            a00[m] = red[0] + red[3] + red[6] + red[9];
            a01[m] = red[1] + red[4] + red[7] + red[10];
            a11[m] = red[2] + red[5] + red[8] + red[11];
        }
        __syncthreads(); // protect red[] before next matrix
    }
}

// ---------------------------------------------------------------------------
// Kernel 3: sequential scan over T per batch + linear head.
// One block (64 lanes) per batch b. Lane t preloads a[., b*T+t]; values are
// broadcast per step via __shfl. All lanes redundantly run the 2x2 closed-form
// eig (rect + logm); lanes 0..16 evaluate the 17-way linear head and store.
//
// 2x2 symmetric closed forms with m=(a+c)/2, d=(a-c)/2, r=sqrt(d^2+b^2),
// lam± = m ± r:   f(H) = ((f(l+)+f(l-))/2) I + ((f(l+)-f(l-))/(2r)) (H - m I)
// rect: f=max(.,EPS) (exact — no spectral assumptions needed); logm: f=log.
// ---------------------------------------------------------------------------
__global__ __launch_bounds__(64) void scan_kernel(
    const float* __restrict__ ws, const float* __restrict__ lin_w,
    const float* __restrict__ lin_b, const float* __restrict__ alpha,
    float* __restrict__ out)
{
    const int b = blockIdx.x;
    const int lane = threadIdx.x;
    const float* a00 = ws + A00_OFF;
    const float* a01 = ws + A01_OFF;
    const float* a11 = ws + A11_OFF;

    const float s  = 1.f / (1.f + expf(-alpha[0]));
    const float os = 1.f - s;

    float lw0 = 0.f, lw1 = 0.f, lw2 = 0.f, lb = 0.f;
    if (lane < NOUT) {
        lw0 = lin_w[lane * 3 + 0];
        lw1 = lin_w[lane * 3 + 1];
        lw2 = lin_w[lane * 3 + 2];
        lb  = lin_b[lane];
    }

    // preload this block's a-sequence: lane t holds a[., b*T+t]
    const int mbase = b * TT;
    float pa00 = a00[mbase + lane];
    float pa01 = a01[mbase + lane];
    float pa11 = a11[mbase + lane];

    // rect(h0 = 0) = EPS * I
    float r00 = RECT_EPS, r01 = 0.f, r11 = RECT_EPS;

    for (int t = 0; t < TT; ++t) {
        float at00 = __shfl(pa00, t);
        float at01 = __shfl(pa01, t);
        float at11 = __shfl(pa11, t);

        float h00 = fmaf(s, at00, os * r00);
        float h01 = fmaf(s, at01, os * r01);
        float h11 = fmaf(s, at11, os * r11);

        float mm = 0.5f * (h00 + h11);
        float dd = 0.5f * (h00 - h11);
        float rr = sqrtf(fmaf(dd, dd, h01 * h01));
        float l1 = mm + rr, l2 = mm - rr;

        // logm(h)
        float lg1 = logf(l1), lg2 = logf(l2);
        float pp = 0.5f * (lg1 + lg2);
        float qq = (rr > 1e-20f) ? (lg1 - lg2) / (2.f * rr) : 0.f;
        float L00 = pp + qq * dd;
        float L01 = qq * h01;
        float L11 = pp - qq * dd;

        if (lane < NOUT) {
            float v = fmaf(L00, lw0, fmaf(L01, lw1, fmaf(L11, lw2, lb)));
            out[(size_t)(mbase + t) * NOUT + lane] = v;
        }

        // rect(h) for the next step (exact eigenvalue clamp)
        float c1 = fmaxf(l1, RECT_EPS), c2 = fmaxf(l2, RECT_EPS);
        float k1 = 0.5f * (c1 + c2);
        float k2 = (rr > 1e-20f) ? (c1 - c2) / (2.f * rr) : 0.f;
        r00 = fmaf(k2, dd, k1);
        r01 = k2 * h01;
        r11 = fmaf(-k2, dd, k1);
    }
}

extern "C" void kernel_launch(void* const* d_in, const int* in_sizes, int n_in,
                              void* d_out, int out_size, void* d_ws, size_t ws_size,
                              hipStream_t stream) {
    const float* x     = (const float*)d_in[0];
    const float* W1    = (const float*)d_in[1];
    const float* W2    = (const float*)d_in[2];
    const float* W3    = (const float*)d_in[3];
    const float* lin_w = (const float*)d_in[4];
    const float* lin_b = (const float*)d_in[5];
    const float* alpha = (const float*)d_in[6];
    float* out = (float*)d_out;
    float* ws  = (float*)d_ws;

    prep_kernel<<<1, 256, 0, stream>>>(W1, W2, W3, ws);
    proj_kernel<<<PROJ_GRID, 256, 0, stream>>>(x, ws);
    scan_kernel<<<BB, 64, 0, stream>>>(ws, lin_w, lin_b, alpha, out);
}